// Round 5
// baseline (46.880 us; speedup 1.0000x reference)
//
#include <hip/hip_runtime.h>
#include <math.h>

// Radon forward, exact reference semantics (rotated-lattice bilinear gather).
//
// Round-11 changes vs round 10 (44.6 us total; tile4 ~38-40 us, occupancy
// re-tile NEUTRAL -> occupancy is not the limiter):
//  * Model: LDS pipe ~16-21 us busy, VALU ~14-16 us busy, wall ~39 us ->
//    ~15 us of serialization from the 0-phase schedule (stage -> vmcnt(0)
//    barrier -> gather -> barrier every subtile).
//  * 2-phase double-buffered pipeline (guide T3 minimum): STAGE(buf^1,k+1)
//    issued BEFORE gather(buf,k); ONE __syncthreads per subtile. Its
//    vmcnt(0) drain lands after a full gather (~1200 cyc) -> stage latency
//    hidden, barriers per subtile halved.
//  * LDS 2 x 17,408 = 34,816 B -> 4 blocks/CU x 4 waves = 16 waves/CU
//    (r10 proved more residency buys nothing).
//  * bbox for all 4 subtiles prefetched to SGPRs up-front; ibi loop fully
//    unrolled (static indexing only -- no VGPR-array scratch, r8 lesson).
//  * Geometry unchanged from r10 (proven): 32j x 24i, TS2=48 (mult of 16,
//    bank fix), TROWS=44, NCHK=17.

#define G       363
#define NT      180
#define PADB    53
#define STEP    (2.0f / 362.0f)
#define DEG2RAD 0.017453292519943295f

#define TS2     48          // tile row length (f32x2 cells), MULTIPLE OF 16
#define TROWS   44          // max tile rows
#define NCHK    17          // max staging chunks (128 cells each)
#define NTILE   (NCHK * 128)   // 2176 cells = 17,408 B per buffer
#define NJB     12          // j-blocks of 32
#define NIB     16          // i-subtiles of 24
#define NJBF    6           // fallback j-blocks of 64
#define CW      262         // canvas cols
#define CH      260         // canvas rows  (image interior at [3..258]x[3..258])
#define NTUPLE  (90 * NJB * NIB)   // 17280

typedef __attribute__((ext_vector_type(2))) float f32x2;

#define GLOAD16(gp, lp) __builtin_amdgcn_global_load_lds(                     \
    (const __attribute__((address_space(1))) void*)(gp),                      \
    (__attribute__((address_space(3))) void*)(lp), 16, 0, 0)

// ---------------- fallback gather kernel (known-good, round 1) -------------
__global__ __launch_bounds__(256) void radon_fwd(
    const float* __restrict__ x, const int* __restrict__ theta,
    float* __restrict__ out)
{
    const int t = blockIdx.x / NJBF, jb = blockIdx.x % NJBF;
    const int jl = threadIdx.x, chunk = threadIdx.y;
    const int j = jb * 64 + jl;
    const float th = (float)theta[t] * DEG2RAD;
    const float c = cosf(th), s = sinf(th);
    const float xj = fmaf((float)j, STEP, -1.0f);
    const float s181 = s * 181.0f, c181 = c * 181.0f;
    const float bx = fmaf(c, xj, 1.0f) * 181.0f;
    const float by = fmaf(-s, xj, 1.0f) * 181.0f;
    const float* img0 = x;
    const float* img1 = x + 65536;
    float acc0 = 0.f, acc1 = 0.f;
    for (int i = chunk; i < G; i += 4) {
        const float xi = fmaf((float)i, STEP, -1.0f);
        const float ix = fmaf(s181, xi, bx);
        const float iy = fmaf(c181, xi, by);
        const float fx = floorf(ix), fy = floorf(iy);
        const int ix0 = (int)fx, iy0 = (int)fy;
        const float wx1 = ix - fx, wy1 = iy - fy;
        const float wx0 = 1.f - wx1, wy0 = 1.f - wy1;
        const int cc0 = ix0 - 53, cc1 = cc0 + 1, rr0 = iy0 - 53, rr1 = rr0 + 1;
        const float wxa = ((unsigned)cc0 < 256u) ? wx0 : 0.f;
        const float wxb = ((unsigned)cc1 < 256u) ? wx1 : 0.f;
        const float wya = ((unsigned)rr0 < 256u) ? wy0 : 0.f;
        const float wyb = ((unsigned)rr1 < 256u) ? wy1 : 0.f;
        const int c0c = min(max(cc0, 0), 255), c1c = min(max(cc1, 0), 255);
        const int r0b = min(max(rr0, 0), 255) << 8, r1b = min(max(rr1, 0), 255) << 8;
        const float w00 = wya * wxa, w01 = wya * wxb, w10 = wyb * wxa, w11 = wyb * wxb;
        acc0 = fmaf(img0[r0b + c0c], w00, acc0);
        acc0 = fmaf(img0[r0b + c1c], w01, acc0);
        acc0 = fmaf(img0[r1b + c0c], w10, acc0);
        acc0 = fmaf(img0[r1b + c1c], w11, acc0);
        acc1 = fmaf(img1[r0b + c0c], w00, acc1);
        acc1 = fmaf(img1[r0b + c1c], w01, acc1);
        acc1 = fmaf(img1[r1b + c0c], w10, acc1);
        acc1 = fmaf(img1[r1b + c1c], w11, acc1);
    }
    __shared__ float red[2][4][64];
    red[0][chunk][jl] = acc0;
    red[1][chunk][jl] = acc1;
    __syncthreads();
    if (threadIdx.y < 2 && j < G) {
        const int n = threadIdx.y;
        out[n * (G * NT) + j * NT + t] =
            red[n][0][jl] + red[n][1][jl] + red[n][2][jl] + red[n][3][jl];
    }
}

// ------------- prep: canvases + bbox table + zero(out) ---------------------
// Block roles by blockIdx.x:
//   [0,81)    : interleave image into guarded canvases (normal + transposed)
//   [81,149)  : bbox table, one tuple (tg,jb,ib) per thread (17280 tuples)
//   [149,277) : zero out (32670 float4)
__global__ __launch_bounds__(256) void prep_k(
    const float* __restrict__ x, const int* __restrict__ theta,
    f32x2* __restrict__ xIc, f32x2* __restrict__ xTIc,
    int4* __restrict__ bbox, float* __restrict__ out)
{
    const int bid = blockIdx.x;
    const int tx = threadIdx.x, ty = threadIdx.y;
    const int tid = ty * 32 + tx;

    if (bid < 81) {
        __shared__ f32x2 tl[32][33];
        const int cx0 = (bid % 9) * 32, cy0 = (bid / 9) * 32;
        #pragma unroll
        for (int dy = 0; dy < 32; dy += 8) {
            const int cy = cy0 + ty + dy, cx = cx0 + tx;
            const int pr = cy - 3, pc = cx - 3;
            f32x2 v = {0.0f, 0.0f};
            if ((unsigned)pr < 256u && (unsigned)pc < 256u) {
                const int p = pr * 256 + pc;
                v.x = x[p]; v.y = x[p + 65536];
            }
            if (cy < CH && cx < CW) xIc[cy * CW + cx] = v;
            tl[ty + dy][tx] = v;
        }
        __syncthreads();
        #pragma unroll
        for (int dy = 0; dy < 32; dy += 8) {
            const int rp = cx0 + ty + dy, cp = cy0 + tx;
            if (rp < CH && cp < CW) xTIc[rp * CW + cp] = tl[tx][ty + dy];
        }
    } else if (bid < 149) {
        const int tuple = (bid - 81) * 256 + tid;
        if (tuple < NTUPLE) {
            const int tg  = tuple / (NJB * NIB), rem = tuple - tg * (NJB * NIB);
            const int jb  = rem / NIB,   ib  = rem - jb * NIB;
            const float thA = (float)theta[tg * 2]     * DEG2RAD;
            const float thB = (float)theta[tg * 2 + 1] * DEG2RAD;
            const float cA = cosf(thA), sA = sinf(thA);
            const float cB = cosf(thB), sB = sinf(thB);
            const float xjm = fmaf((float)(jb * 32),      STEP, -1.0f);
            const float xjM = fmaf((float)(jb * 32 + 31), STEP, -1.0f);
            const float xim = fmaf((float)(ib * 24),      STEP, -1.0f);
            const float xiM = fmaf((float)(ib * 24 + 23), STEP, -1.0f);
            float ixmin = 1e30f, ixmax = -1e30f, iymin = 1e30f, iymax = -1e30f;
            #pragma unroll
            for (int qq = 0; qq < 8; ++qq) {
                const float cc  = (qq & 4) ? cB : cA;
                const float ss  = (qq & 4) ? sB : sA;
                const float xjc = (qq & 1) ? xjM : xjm;
                const float xic = (qq & 2) ? xiM : xim;
                const float bxq = fmaf(cc,  xjc, 1.0f) * 181.0f;
                const float byq = fmaf(-ss, xjc, 1.0f) * 181.0f;
                const float ixq = fmaf(ss * 181.0f, xic, bxq);
                const float iyq = fmaf(cc * 181.0f, xic, byq);
                ixmin = fminf(ixmin, ixq); ixmax = fmaxf(ixmax, ixq);
                iymin = fminf(iymin, iyq); iymax = fmaxf(iymax, iyq);
            }
            const int caseA = (fabsf(cA) + fabsf(cB) >= fabsf(sA) + fabsf(sB));
            const float Umin = caseA ? iymin : ixmin;
            const float Umax = caseA ? iymax : ixmax;
            const float Vmin = caseA ? ixmin : iymin;
            const int r0 = (int)floorf(Umin) - 1;
            const int c0 = (int)floorf(Vmin) - 1;
            int rows = (int)floorf(Umax) - (int)floorf(Umin) + 4;
            rows = min(rows, TROWS);
            const int nchunk = (rows * TS2 + 127) >> 7;     // <= 17
            const int r0p = r0 - PADB, c0p = c0 - PADB;
            const int tyLast = (nchunk * 128 - 1) / TS2;
            const int safe = (r0p >= -3) && (r0p + tyLast <= 256)
                          && (c0p >= -3) && (c0p + (TS2 - 1) <= 257);
            bbox[tuple] = make_int4(r0p, c0p,
                                    nchunk | (safe << 8) | (caseA << 9),
                                    -(r0 * TS2 + c0));
        }
    } else {
        const int idx = (bid - 149) * 256 + tid;            // out: 130680 f32
        if (idx < 32670) ((float4*)out)[idx] = make_float4(0.f, 0.f, 0.f, 0.f);
    }
}

// ---------------- staging: 16B/lane global_load_lds, linear LDS dest -------
template<bool SAFE>
__device__ __forceinline__ void stage_direct(f32x2* tileB, const f32x2* __restrict__ srcC,
    int r0p, int c0p, int nchunk, int wid, int lane2)
{
    const int B = (r0p + 3) * CW + (c0p + 3);
    for (int h = wid; h < nchunk; h += 4) {
        const int hs   = __builtin_amdgcn_readfirstlane(h);
        const int cell = (hs << 7) + lane2;
        const int tyc  = cell / TS2;
        const int txc  = cell - tyc * TS2;
        int idx;
        if (SAFE) {
            idx = tyc * CW + txc + B;
        } else {
            const int rc = min(max(r0p + tyc, -3), 256) + 3;
            const int cc = min(max(c0p + txc, -3), 257) + 3;
            idx = rc * CW + cc;
        }
        GLOAD16(srcC + idx, (char*)tileB + (hs << 10));
    }
}

// ---------------- gather inner loop (6 i-steps) ----------------------------
template<bool TAIL>
__device__ __forceinline__ void gather6(const f32x2* __restrict__ tl,
    float Uf, float Vf, float dU, float dV, int nbase, int iexc,
    f32x2& acc0, f32x2& acc1)
{
    #pragma unroll
    for (int k = 0; k < 6; ++k) {
        const float fU = floorf(Uf), fV = floorf(Vf);
        float wU1 = Uf - fU;
        const float wV1 = Vf - fV;
        float wU0 = 1.0f - wU1;
        const float wV0 = 1.0f - wV1;
        // fU*48+fV exact (integers < 2^24); rel = ty*48+tx in [0, 2112)
        const int rel = (int)fmaf(fU, (float)TS2, fV) + nbase;
        const f32x2 t00 = tl[rel];
        const f32x2 t01 = tl[rel + 1];
        const f32x2 t10 = tl[rel + TS2];
        const f32x2 t11 = tl[rel + TS2 + 1];
        if (TAIL && k >= iexc) { wU0 = 0.0f; wU1 = 0.0f; }   // phantom i >= G
        f32x2 r0v = t00 * (f32x2){wV0, wV0};
        r0v = __builtin_elementwise_fma(t01, (f32x2){wV1, wV1}, r0v);
        f32x2 r1v = t10 * (f32x2){wV0, wV0};
        r1v = __builtin_elementwise_fma(t11, (f32x2){wV1, wV1}, r1v);
        acc0 = __builtin_elementwise_fma(r0v, (f32x2){wU0, wU0}, acc0);
        acc1 = __builtin_elementwise_fma(r1v, (f32x2){wU1, wU1}, acc1);
        Uf += dU; Vf += dV;
    }
}

// ---------------- main tiled gather (2-phase double-buffered) --------------
__global__ __launch_bounds__(256) void radon_tile5(
    const f32x2* __restrict__ xIc, const f32x2* __restrict__ xTIc,
    const int*   __restrict__ theta, const int4* __restrict__ bbox,
    float* __restrict__ out)
{
    __shared__ f32x2 tile[2 * NTILE];      // 34,816 B -> 4 blocks/CU

    const int blk  = blockIdx.x;           // 0..1079
    const int z    = blockIdx.y;           // 0..3, handles ib = 4z..4z+3
    const int tg   = blk / NJB;
    const int jb   = blk - tg * NJB;
    const int tid  = threadIdx.x;
    const int lane = tid & 63;
    const int wid  = tid >> 6;             // 0..3
    const int a    = wid >> 1;             // angle of pair
    const int wj   = wid & 1;              // j half (16)
    const int jl   = lane & 15;            // j lane
    const int kk   = lane >> 4;            // i 6-group (0..3)

    const int t = tg * 2 + a;
    const float th = (float)theta[t] * DEG2RAD;
    const float c = cosf(th), s = sinf(th);
    const float s181 = s * 181.0f, c181 = c * 181.0f;

    const int   j  = jb * 32 + wj * 16 + jl;   // phantom j >= 363 ok
    const float xj = fmaf((float)j, STEP, -1.0f);
    const float bx = fmaf(c,  xj, 1.0f) * 181.0f;
    const float by = fmaf(-s, xj, 1.0f) * 181.0f;

    const int lane2 = lane * 2;
    const float fiofs = (float)(kk * 6);

    // ---- prefetch all 4 subtile bboxes into SGPRs (static indexing) ----
    const int tb = (tg * NJB + jb) * NIB + z * 4;
    int r0pA[4], c0pA[4], flA[4], nbA[4];
    #pragma unroll
    for (int u = 0; u < 4; ++u) {
        const int4 bb = bbox[tb + u];
        r0pA[u] = __builtin_amdgcn_readfirstlane(bb.x);
        c0pA[u] = __builtin_amdgcn_readfirstlane(bb.y);
        flA[u]  = __builtin_amdgcn_readfirstlane(bb.z);
        nbA[u]  = __builtin_amdgcn_readfirstlane(bb.w);
    }

    const int caseA = (flA[0] >> 9) & 1;
    const f32x2* __restrict__ srcC = caseA ? xIc : xTIc;

    const float slopeU = caseA ? c181 : s181;
    const float slopeV = caseA ? s181 : c181;
    const float dU = slopeU * STEP;
    const float dV = slopeV * STEP;
    const float U00 = (caseA ? by : bx) - slopeU;
    const float V00 = (caseA ? bx : by) - slopeV;

    f32x2 acc0 = {0.0f, 0.0f}, acc1 = {0.0f, 0.0f};
    const int ib0 = z * 4;

    // ---- prologue: stage subtile 0 into buffer 0 ----
    if (flA[0] & 256) stage_direct<true >(tile, srcC, r0pA[0], c0pA[0], flA[0] & 255, wid, lane2);
    else              stage_direct<false>(tile, srcC, r0pA[0], c0pA[0], flA[0] & 255, wid, lane2);
    __syncthreads();                       // drain vmcnt -> buf0 ready

    // ---- 2-phase pipeline: stage(k+1) before gather(k), 1 barrier/iter ----
    #pragma unroll
    for (int ibi = 0; ibi < 4; ++ibi) {
        if (ibi < 3) {
            f32x2* nxt = tile + ((ibi + 1) & 1) * NTILE;
            if (flA[ibi + 1] & 256)
                stage_direct<true >(nxt, srcC, r0pA[ibi + 1], c0pA[ibi + 1],
                                    flA[ibi + 1] & 255, wid, lane2);
            else
                stage_direct<false>(nxt, srcC, r0pA[ibi + 1], c0pA[ibi + 1],
                                    flA[ibi + 1] & 255, wid, lane2);
        }

        // ---- gather current buffer: 6 samples/lane, incremental U/V ----
        const f32x2* cur = tile + (ibi & 1) * NTILE;
        const int i0 = (ib0 + ibi) * 24;
        const float fi = (float)i0 + fiofs;
        const float Uf = fmaf(dU, fi, U00);
        const float Vf = fmaf(dV, fi, V00);
        const int ibase = i0 + kk * 6;

        if (i0 + 23 < G) {                 // block-uniform
            gather6<false>(cur, Uf, Vf, dU, dV, nbA[ibi], 6, acc0, acc1);
        } else {
            gather6<true>(cur, Uf, Vf, dU, dV, nbA[ibi], G - ibase, acc0, acc1);
        }

        if (ibi < 3) __syncthreads();      // drains vmcnt of stage(k+1);
                                           // also guards buf reuse next iter
    }

    // ---- reduce i-groups (lanes jl, jl+16, jl+32, jl+48) via shfl ----
    f32x2 v = acc0 + acc1;
    v.x += __shfl_xor(v.x, 16);
    v.y += __shfl_xor(v.y, 16);
    v.x += __shfl_xor(v.x, 32);
    v.y += __shfl_xor(v.y, 32);

    if (lane < 16 && j < G) {
        atomicAdd(&out[j * NT + t],          v.x);   // n = 0
        atomicAdd(&out[G * NT + j * NT + t], v.y);   // n = 1
    }
}

extern "C" void kernel_launch(void* const* d_in, const int* in_sizes, int n_in,
                              void* d_out, int out_size, void* d_ws, size_t ws_size,
                              hipStream_t stream) {
    const float* x     = (const float*)d_in[0];
    const int*   theta = (const int*)d_in[1];
    float*       out   = (float*)d_out;

    const size_t XIC_OFF  = 0;
    const size_t XTIC_OFF = (size_t)CH * CW * 8;                 // 544,960
    const size_t BBOX_OFF = 2 * XTIC_OFF;                        // 1,089,920
    const size_t NEED     = BBOX_OFF + (size_t)NTUPLE * 16;      // ~1.30 MiB

    if (ws_size < NEED) {   // fallback: known-good gather kernel
        hipLaunchKernelGGL(radon_fwd, dim3(NT * NJBF), dim3(64, 4), 0, stream,
                           x, theta, out);
        return;
    }

    f32x2* xIc  = (f32x2*)((char*)d_ws + XIC_OFF);
    f32x2* xTIc = (f32x2*)((char*)d_ws + XTIC_OFF);
    int4*  bbox = (int4*)((char*)d_ws + BBOX_OFF);

    hipLaunchKernelGGL(prep_k, dim3(277), dim3(32, 8), 0, stream,
                       x, theta, xIc, xTIc, bbox, out);
    hipLaunchKernelGGL(radon_tile5, dim3(1080, 4), dim3(256), 0, stream,
                       xIc, xTIc, theta, bbox, out);
}

// Round 6
// 42.433 us; speedup vs baseline: 1.1048x; 1.1048x over previous
//
#include <hip/hip_runtime.h>
#include <hip/hip_fp16.h>
#include <math.h>

// Radon forward, exact reference semantics (rotated-lattice bilinear gather).
//
// Round-12 changes vs round 11 (46.9 us total; tile5 41 us; dbuf NEGATIVE):
//  * Post-mortem r9-r11: wall ~39-41 us across 3 schedule variants; per-CU
//    LDS pipe ~19 us busy + VALU ~19 us busy and wall ~= SUM (intra-wave
//    VALU->DS->FMA alternation; TLP doesn't overlap them -- r10 proved).
//    => shrink per-sample work on BOTH pipes instead of rescheduling.
//  * Canvases packed as u32 = {f16 img0, f16 img1} (4 B cells):
//    - gather: 4x ds_read_b32 (2 cyc base vs 4 for b64) -> LDS pipe halves
//    - banks = cell mod 32, row stride TS2=64 == 0 mod 32 -> pure tx-banks,
//      64 lanes / 32 banks ~= 2/bank = FREE -> conflicts ~gone
//    - unpack folds into v_fma_mix_f32 (fmaf(half2float(h), w, acc))
//    - staging bytes halve; TS2=64 -> staging addr is shifts (no magic div)
//    - precision: f16 err 5e-4/tap -> accumulated ~0.007 << 0.25 absmax
//  * Geometry: 32j x 48i subtiles. U-span <= sqrt(47^2+31^2)+4.8 ~ 61 ->
//    TROWS=68 (slack 3). V-span <= 55.2+4.8 -> col index <= ceil(59.9)+3
//    = 63 fits TS2=64. Guard ring 4-wide (clamped 16B lane loads land
//    fully in zero guard). Tile 17,408 B single-buffer, r10 0-phase
//    schedule (proven best of the three).

#define G       363
#define NT      180
#define PADB    53
#define STEP    (2.0f / 362.0f)
#define DEG2RAD 0.017453292519943295f

#define TS2     64          // tile row length (u32 cells), POWER OF 2, %32==0
#define TROWS   68          // max tile rows
#define NCHK    17          // max staging chunks (256 cells = 1 KiB each)
#define NTILE   (NCHK * 256)   // 4352 cells = 17,408 B -> ~8 blocks/CU
#define NJB     12          // j-blocks of 32
#define NIB     8           // i-subtiles of 48
#define NJBF    6           // fallback j-blocks of 64
#define CW      264         // canvas cols (4 guard + 256 + 4 guard)
#define CH      264         // canvas rows
#define NTUPLE  (90 * NJB * NIB)   // 8640

#define GLOAD16(gp, lp) __builtin_amdgcn_global_load_lds(                     \
    (const __attribute__((address_space(1))) void*)(gp),                      \
    (__attribute__((address_space(3))) void*)(lp), 16, 0, 0)

__device__ __forceinline__ float hlo(unsigned r) {
    return __half2float(__ushort_as_half((unsigned short)(r & 0xffffu)));
}
__device__ __forceinline__ float hhi(unsigned r) {
    return __half2float(__ushort_as_half((unsigned short)(r >> 16)));
}

// ---------------- fallback gather kernel (known-good, round 1) -------------
__global__ __launch_bounds__(256) void radon_fwd(
    const float* __restrict__ x, const int* __restrict__ theta,
    float* __restrict__ out)
{
    const int t = blockIdx.x / NJBF, jb = blockIdx.x % NJBF;
    const int jl = threadIdx.x, chunk = threadIdx.y;
    const int j = jb * 64 + jl;
    const float th = (float)theta[t] * DEG2RAD;
    const float c = cosf(th), s = sinf(th);
    const float xj = fmaf((float)j, STEP, -1.0f);
    const float s181 = s * 181.0f, c181 = c * 181.0f;
    const float bx = fmaf(c, xj, 1.0f) * 181.0f;
    const float by = fmaf(-s, xj, 1.0f) * 181.0f;
    const float* img0 = x;
    const float* img1 = x + 65536;
    float acc0 = 0.f, acc1 = 0.f;
    for (int i = chunk; i < G; i += 4) {
        const float xi = fmaf((float)i, STEP, -1.0f);
        const float ix = fmaf(s181, xi, bx);
        const float iy = fmaf(c181, xi, by);
        const float fx = floorf(ix), fy = floorf(iy);
        const int ix0 = (int)fx, iy0 = (int)fy;
        const float wx1 = ix - fx, wy1 = iy - fy;
        const float wx0 = 1.f - wx1, wy0 = 1.f - wy1;
        const int cc0 = ix0 - 53, cc1 = cc0 + 1, rr0 = iy0 - 53, rr1 = rr0 + 1;
        const float wxa = ((unsigned)cc0 < 256u) ? wx0 : 0.f;
        const float wxb = ((unsigned)cc1 < 256u) ? wx1 : 0.f;
        const float wya = ((unsigned)rr0 < 256u) ? wy0 : 0.f;
        const float wyb = ((unsigned)rr1 < 256u) ? wy1 : 0.f;
        const int c0c = min(max(cc0, 0), 255), c1c = min(max(cc1, 0), 255);
        const int r0b = min(max(rr0, 0), 255) << 8, r1b = min(max(rr1, 0), 255) << 8;
        const float w00 = wya * wxa, w01 = wya * wxb, w10 = wyb * wxa, w11 = wyb * wxb;
        acc0 = fmaf(img0[r0b + c0c], w00, acc0);
        acc0 = fmaf(img0[r0b + c1c], w01, acc0);
        acc0 = fmaf(img0[r1b + c0c], w10, acc0);
        acc0 = fmaf(img0[r1b + c1c], w11, acc0);
        acc1 = fmaf(img1[r0b + c0c], w00, acc1);
        acc1 = fmaf(img1[r0b + c1c], w01, acc1);
        acc1 = fmaf(img1[r1b + c0c], w10, acc1);
        acc1 = fmaf(img1[r1b + c1c], w11, acc1);
    }
    __shared__ float red[2][4][64];
    red[0][chunk][jl] = acc0;
    red[1][chunk][jl] = acc1;
    __syncthreads();
    if (threadIdx.y < 2 && j < G) {
        const int n = threadIdx.y;
        out[n * (G * NT) + j * NT + t] =
            red[n][0][jl] + red[n][1][jl] + red[n][2][jl] + red[n][3][jl];
    }
}

// ------------- prep: f16x2 canvases + bbox table + zero(out) ---------------
// Block roles by blockIdx.x:
//   [0,81)    : pack image pair into guarded u32 canvases (normal+transposed)
//   [81,115)  : bbox table, one tuple (tg,jb,ib) per thread (8640 tuples)
//   [115,243) : zero out (32670 float4)
__global__ __launch_bounds__(256) void prep_k(
    const float* __restrict__ x, const int* __restrict__ theta,
    unsigned* __restrict__ xIh, unsigned* __restrict__ xTIh,
    int4* __restrict__ bbox, float* __restrict__ out)
{
    const int bid = blockIdx.x;
    const int tx = threadIdx.x, ty = threadIdx.y;
    const int tid = ty * 32 + tx;

    if (bid < 81) {
        __shared__ unsigned tl[32][33];
        const int cx0 = (bid % 9) * 32, cy0 = (bid / 9) * 32;
        #pragma unroll
        for (int dy = 0; dy < 32; dy += 8) {
            const int cy = cy0 + ty + dy, cx = cx0 + tx;
            const int pr = cy - 4, pc = cx - 4;
            unsigned v = 0u;
            if ((unsigned)pr < 256u && (unsigned)pc < 256u) {
                const int p = pr * 256 + pc;
                const unsigned short a = __half_as_ushort(__float2half_rn(x[p]));
                const unsigned short b = __half_as_ushort(__float2half_rn(x[p + 65536]));
                v = (unsigned)a | ((unsigned)b << 16);
            }
            if (cy < CH && cx < CW) xIh[cy * CW + cx] = v;
            tl[ty + dy][tx] = v;
        }
        __syncthreads();
        #pragma unroll
        for (int dy = 0; dy < 32; dy += 8) {
            const int rp = cx0 + ty + dy, cp = cy0 + tx;
            if (rp < CH && cp < CW) xTIh[rp * CW + cp] = tl[tx][ty + dy];
        }
    } else if (bid < 115) {
        const int tuple = (bid - 81) * 256 + tid;
        if (tuple < NTUPLE) {
            const int tg  = tuple / (NJB * NIB), rem = tuple - tg * (NJB * NIB);
            const int jb  = rem / NIB,   ib  = rem - jb * NIB;
            const float thA = (float)theta[tg * 2]     * DEG2RAD;
            const float thB = (float)theta[tg * 2 + 1] * DEG2RAD;
            const float cA = cosf(thA), sA = sinf(thA);
            const float cB = cosf(thB), sB = sinf(thB);
            const float xjm = fmaf((float)(jb * 32),      STEP, -1.0f);
            const float xjM = fmaf((float)(jb * 32 + 31), STEP, -1.0f);
            const float xim = fmaf((float)(ib * 48),      STEP, -1.0f);
            const float xiM = fmaf((float)(ib * 48 + 47), STEP, -1.0f);
            float ixmin = 1e30f, ixmax = -1e30f, iymin = 1e30f, iymax = -1e30f;
            #pragma unroll
            for (int qq = 0; qq < 8; ++qq) {
                const float cc  = (qq & 4) ? cB : cA;
                const float ss  = (qq & 4) ? sB : sA;
                const float xjc = (qq & 1) ? xjM : xjm;
                const float xic = (qq & 2) ? xiM : xim;
                const float bxq = fmaf(cc,  xjc, 1.0f) * 181.0f;
                const float byq = fmaf(-ss, xjc, 1.0f) * 181.0f;
                const float ixq = fmaf(ss * 181.0f, xic, bxq);
                const float iyq = fmaf(cc * 181.0f, xic, byq);
                ixmin = fminf(ixmin, ixq); ixmax = fmaxf(ixmax, ixq);
                iymin = fminf(iymin, iyq); iymax = fmaxf(iymax, iyq);
            }
            const int caseA = (fabsf(cA) + fabsf(cB) >= fabsf(sA) + fabsf(sB));
            const float Umin = caseA ? iymin : ixmin;
            const float Umax = caseA ? iymax : ixmax;
            const float Vmin = caseA ? ixmin : iymin;
            const int r0 = (int)floorf(Umin) - 1;
            const int c0 = (int)floorf(Vmin) - 1;
            int rows = (int)floorf(Umax) - (int)floorf(Umin) + 4;
            rows = min(rows, TROWS);
            const int nchunk = (rows + 3) >> 2;             // 256-cell chunks
            const int r0p = r0 - PADB, c0p = c0 - PADB;
            const int tyLast = (nchunk * 256 - 1) >> 6;     // /TS2
            const int safe = (r0p >= -4) && (r0p + tyLast <= 259)
                          && (c0p >= -4) && (c0p <= 196);
            bbox[tuple] = make_int4(r0p, c0p,
                                    nchunk | (safe << 8) | (caseA << 9),
                                    -(r0 * TS2 + c0));
        }
    } else {
        const int idx = (bid - 115) * 256 + tid;            // out: 130680 f32
        if (idx < 32670) ((float4*)out)[idx] = make_float4(0.f, 0.f, 0.f, 0.f);
    }
}

// ---------------- staging: 16B/lane global_load_lds, linear LDS dest -------
template<bool SAFE>
__device__ __forceinline__ void stage_direct(unsigned* tileB,
    const unsigned* __restrict__ srcC,
    int r0p, int c0p, int nchunk, int wid, int lane)
{
    const int B = (r0p + 4) * CW + (c0p + 4);
    for (int h = wid; h < nchunk; h += 4) {
        const int hs   = __builtin_amdgcn_readfirstlane(h);
        const int cell = (hs << 8) + (lane << 2);   // 4 cells / lane, row-pure
        const int tyc  = cell >> 6;                 // /TS2
        const int txc  = cell & 63;
        int idx;
        if (SAFE) {
            idx = tyc * CW + txc + B;
        } else {
            // clamp into 4-wide zero guard: 16B lane-read stays all-guard
            const int rc = min(max(r0p + tyc, -4), 256) + 4;
            const int cc = min(max(c0p + txc, -4), 256) + 4;
            idx = rc * CW + cc;
        }
        GLOAD16(srcC + idx, (char*)tileB + (hs << 10));
    }
}

// ---------------- gather inner loop (6 i-steps, f16 mix-FMA) ---------------
template<bool TAIL>
__device__ __forceinline__ void gather6(const unsigned* __restrict__ tl,
    float Uf0, float Vf0, float dU, float dV, int nbase, int iexc,
    float& a0x, float& a0y, float& a1x, float& a1y)
{
    #pragma unroll
    for (int k = 0; k < 6; ++k) {
        const float Uf = fmaf((float)k, dU, Uf0);   // independent, no chain
        const float Vf = fmaf((float)k, dV, Vf0);
        const float fU = floorf(Uf), fV = floorf(Vf);
        float wU1 = Uf - fU;
        const float wV1 = Vf - fV;
        float wU0 = 1.0f - wU1;
        const float wV0 = 1.0f - wV1;
        // fU*64+fV exact (integers < 2^24); rel = ty*64+tx in [0, 4352)
        const int rel = (int)fmaf(fU, (float)TS2, fV) + nbase;
        const unsigned r00 = tl[rel];
        const unsigned r01 = tl[rel + 1];
        const unsigned r10 = tl[rel + TS2];
        const unsigned r11 = tl[rel + TS2 + 1];
        if (TAIL && k >= iexc) { wU0 = 0.0f; wU1 = 0.0f; }   // phantom i >= G
        const float w00 = wU0 * wV0, w01 = wU0 * wV1;
        const float w10 = wU1 * wV0, w11 = wU1 * wV1;
        a0x = fmaf(hlo(r00), w00, a0x);     // v_fma_mix_f32 candidates
        a0x = fmaf(hlo(r01), w01, a0x);
        a1x = fmaf(hlo(r10), w10, a1x);
        a1x = fmaf(hlo(r11), w11, a1x);
        a0y = fmaf(hhi(r00), w00, a0y);
        a0y = fmaf(hhi(r01), w01, a0y);
        a1y = fmaf(hhi(r10), w10, a1y);
        a1y = fmaf(hhi(r11), w11, a1y);
    }
}

// ---------------- main tiled gather ----------------------------------------
__global__ __launch_bounds__(256) void radon_tile6(
    const unsigned* __restrict__ xIh, const unsigned* __restrict__ xTIh,
    const int*   __restrict__ theta, const int4* __restrict__ bbox,
    float* __restrict__ out)
{
    __shared__ unsigned tile[NTILE];       // 17,408 B

    const int blk  = blockIdx.x;           // 0..1079
    const int z    = blockIdx.y;           // 0..3, handles ib = 2z, 2z+1
    const int tg   = blk / NJB;
    const int jb   = blk - tg * NJB;
    const int tid  = threadIdx.x;
    const int lane = tid & 63;
    const int wid  = tid >> 6;             // 0..3
    const int a    = wid >> 1;             // angle of pair
    const int wj   = wid & 1;              // j half (16)
    const int jl   = lane & 15;            // j lane
    const int kk   = lane >> 4;            // i 12-group (0..3)

    const int t = tg * 2 + a;
    const float th = (float)theta[t] * DEG2RAD;
    const float c = cosf(th), s = sinf(th);
    const float s181 = s * 181.0f, c181 = c * 181.0f;

    const int   j  = jb * 32 + wj * 16 + jl;   // phantom j >= 363 ok
    const float xj = fmaf((float)j, STEP, -1.0f);
    const float bx = fmaf(c,  xj, 1.0f) * 181.0f;
    const float by = fmaf(-s, xj, 1.0f) * 181.0f;

    const float fiofs = (float)(kk * 12);

    // ---- per-pair uniforms (case identical across the subtiles) ----
    const int tb = (tg * NJB + jb) * NIB + z * 2;
    const int caseA = (__builtin_amdgcn_readfirstlane(bbox[tb].z) >> 9) & 1;
    const unsigned* __restrict__ srcC = caseA ? xIh : xTIh;

    const float slopeU = caseA ? c181 : s181;
    const float slopeV = caseA ? s181 : c181;
    const float dU = slopeU * STEP;
    const float dV = slopeV * STEP;
    const float U00 = (caseA ? by : bx) - slopeU;
    const float V00 = (caseA ? bx : by) - slopeV;

    float a0x = 0.f, a0y = 0.f, a1x = 0.f, a1y = 0.f;

    #pragma unroll
    for (int ibi = 0; ibi < 2; ++ibi) {
        const int ib = z * 2 + ibi;
        const int4 bb = bbox[tb + ibi];
        const int r0p    = __builtin_amdgcn_readfirstlane(bb.x);
        const int c0p    = __builtin_amdgcn_readfirstlane(bb.y);
        const int flags  = __builtin_amdgcn_readfirstlane(bb.z);
        const int nbase  = __builtin_amdgcn_readfirstlane(bb.w);
        const int nchunk = flags & 255;
        const int safe   = (flags >> 8) & 1;

        __syncthreads();                   // previous tile fully consumed

        if (safe) stage_direct<true >(tile, srcC, r0p, c0p, nchunk, wid, lane);
        else      stage_direct<false>(tile, srcC, r0p, c0p, nchunk, wid, lane);
        __syncthreads();                   // drains vmcnt -> tile ready

        // ---- gather: 12 samples/lane as 2x gather6 ----
        const int i0 = ib * 48;
        const float fi  = (float)i0 + fiofs;
        const float Uf1 = fmaf(dU, fi, U00);
        const float Vf1 = fmaf(dV, fi, V00);
        const float Uf2 = fmaf(dU, fi + 6.0f, U00);
        const float Vf2 = fmaf(dV, fi + 6.0f, V00);
        const int ibase = i0 + kk * 12;

        if (i0 + 47 < G) {                 // block-uniform
            gather6<false>(tile, Uf1, Vf1, dU, dV, nbase, 6, a0x, a0y, a1x, a1y);
            gather6<false>(tile, Uf2, Vf2, dU, dV, nbase, 6, a0x, a0y, a1x, a1y);
        } else {
            gather6<true>(tile, Uf1, Vf1, dU, dV, nbase, G - ibase,     a0x, a0y, a1x, a1y);
            gather6<true>(tile, Uf2, Vf2, dU, dV, nbase, G - ibase - 6, a0x, a0y, a1x, a1y);
        }
    }

    // ---- reduce i-groups (lanes jl, jl+16, jl+32, jl+48) via shfl ----
    float vx = a0x + a1x;
    float vy = a0y + a1y;
    vx += __shfl_xor(vx, 16);
    vy += __shfl_xor(vy, 16);
    vx += __shfl_xor(vx, 32);
    vy += __shfl_xor(vy, 32);

    if (lane < 16 && j < G) {
        atomicAdd(&out[j * NT + t],          vx);   // n = 0
        atomicAdd(&out[G * NT + j * NT + t], vy);   // n = 1
    }
}

extern "C" void kernel_launch(void* const* d_in, const int* in_sizes, int n_in,
                              void* d_out, int out_size, void* d_ws, size_t ws_size,
                              hipStream_t stream) {
    const float* x     = (const float*)d_in[0];
    const int*   theta = (const int*)d_in[1];
    float*       out   = (float*)d_out;

    const size_t XIH_OFF  = 0;
    const size_t XTIH_OFF = (size_t)CH * CW * 4;                 // 278,784
    const size_t BBOX_OFF = 2 * XTIH_OFF;                        // 557,568
    const size_t NEED     = BBOX_OFF + (size_t)NTUPLE * 16;      // ~696 KB

    if (ws_size < NEED) {   // fallback: known-good gather kernel
        hipLaunchKernelGGL(radon_fwd, dim3(NT * NJBF), dim3(64, 4), 0, stream,
                           x, theta, out);
        return;
    }

    unsigned* xIh  = (unsigned*)((char*)d_ws + XIH_OFF);
    unsigned* xTIh = (unsigned*)((char*)d_ws + XTIH_OFF);
    int4*     bbox = (int4*)((char*)d_ws + BBOX_OFF);

    hipLaunchKernelGGL(prep_k, dim3(243), dim3(32, 8), 0, stream,
                       x, theta, xIh, xTIh, bbox, out);
    hipLaunchKernelGGL(radon_tile6, dim3(1080, 4), dim3(256), 0, stream,
                       xIh, xTIh, theta, bbox, out);
}

// Round 7
// 34.055 us; speedup vs baseline: 1.3766x; 1.2460x over previous
//
#include <hip/hip_runtime.h>
#include <hip/hip_fp16.h>
#include <math.h>

// Radon forward, exact reference semantics (rotated-lattice bilinear gather).
//
// Round-13 changes vs round 12 (42.4 us total; tile6 < 38.4 us, VALU-bound):
//  * Post-mortem r12: f16 cells halved LDS but the unpack path (8 scalar
//    v_fma_mix + 4 weight muls) kept ~23 VALU/sample -> VALU-issue-bound
//    (~31 us busy of ~38 us wall).
//  * Packed-f16 lerp interp: cells are native __half2 {img0,img1}; the
//    4-tap weighted sum == two-lerp form in v_pk_fma_f16 (both images per
//    instr): 2 cvt_pkrtz broadcasts + 3 hsub2 + 3 hfma2 + 1 hadd2 = 9 ops
//    vs 14. Algebraically identical weights; f16 rounding well under the
//    0.25 tolerance (acc flushed to f32 every 6 taps; est err <= ~0.05).
//  * nbase folded into per-subtile U00/V00 (exact integer subtract in f32)
//    -> rel = (int)fmaf(fU,64,fV), no +nbase per sample.
//  * Net ~17 VALU + 2 DS (ds_read2_b32 merges) per sample, was ~23 + 4.
//  * z: 4 -> 2 (grid 2160 blocks, 4 subtiles/block): halves block-level
//    prologue/epilogue/atomic overhead; still ~8.4 blocks/CU.
//  * Geometry/schedule unchanged from r12 (0-phase, single 17,408 B tile).

#define G       363
#define NT      180
#define PADB    53
#define STEP    (2.0f / 362.0f)
#define DEG2RAD 0.017453292519943295f

#define TS2     64          // tile row length (u32 cells), POWER OF 2, %32==0
#define TROWS   68          // max tile rows
#define NCHK    17          // max staging chunks (256 cells = 1 KiB each)
#define NTILE   (NCHK * 256)   // 4352 cells = 17,408 B -> 8 blocks/CU
#define NJB     12          // j-blocks of 32
#define NIB     8           // i-subtiles of 48
#define NJBF    6           // fallback j-blocks of 64
#define CW      264         // canvas cols (4 guard + 256 + 4 guard)
#define CH      264         // canvas rows
#define NTUPLE  (90 * NJB * NIB)   // 8640

#define GLOAD16(gp, lp) __builtin_amdgcn_global_load_lds(                     \
    (const __attribute__((address_space(1))) void*)(gp),                      \
    (__attribute__((address_space(3))) void*)(lp), 16, 0, 0)

// ---------------- fallback gather kernel (known-good, round 1) -------------
__global__ __launch_bounds__(256) void radon_fwd(
    const float* __restrict__ x, const int* __restrict__ theta,
    float* __restrict__ out)
{
    const int t = blockIdx.x / NJBF, jb = blockIdx.x % NJBF;
    const int jl = threadIdx.x, chunk = threadIdx.y;
    const int j = jb * 64 + jl;
    const float th = (float)theta[t] * DEG2RAD;
    const float c = cosf(th), s = sinf(th);
    const float xj = fmaf((float)j, STEP, -1.0f);
    const float s181 = s * 181.0f, c181 = c * 181.0f;
    const float bx = fmaf(c, xj, 1.0f) * 181.0f;
    const float by = fmaf(-s, xj, 1.0f) * 181.0f;
    const float* img0 = x;
    const float* img1 = x + 65536;
    float acc0 = 0.f, acc1 = 0.f;
    for (int i = chunk; i < G; i += 4) {
        const float xi = fmaf((float)i, STEP, -1.0f);
        const float ix = fmaf(s181, xi, bx);
        const float iy = fmaf(c181, xi, by);
        const float fx = floorf(ix), fy = floorf(iy);
        const int ix0 = (int)fx, iy0 = (int)fy;
        const float wx1 = ix - fx, wy1 = iy - fy;
        const float wx0 = 1.f - wx1, wy0 = 1.f - wy1;
        const int cc0 = ix0 - 53, cc1 = cc0 + 1, rr0 = iy0 - 53, rr1 = rr0 + 1;
        const float wxa = ((unsigned)cc0 < 256u) ? wx0 : 0.f;
        const float wxb = ((unsigned)cc1 < 256u) ? wx1 : 0.f;
        const float wya = ((unsigned)rr0 < 256u) ? wy0 : 0.f;
        const float wyb = ((unsigned)rr1 < 256u) ? wy1 : 0.f;
        const int c0c = min(max(cc0, 0), 255), c1c = min(max(cc1, 0), 255);
        const int r0b = min(max(rr0, 0), 255) << 8, r1b = min(max(rr1, 0), 255) << 8;
        const float w00 = wya * wxa, w01 = wya * wxb, w10 = wyb * wxa, w11 = wyb * wxb;
        acc0 = fmaf(img0[r0b + c0c], w00, acc0);
        acc0 = fmaf(img0[r0b + c1c], w01, acc0);
        acc0 = fmaf(img0[r1b + c0c], w10, acc0);
        acc0 = fmaf(img0[r1b + c1c], w11, acc0);
        acc1 = fmaf(img1[r0b + c0c], w00, acc1);
        acc1 = fmaf(img1[r0b + c1c], w01, acc1);
        acc1 = fmaf(img1[r1b + c0c], w10, acc1);
        acc1 = fmaf(img1[r1b + c1c], w11, acc1);
    }
    __shared__ float red[2][4][64];
    red[0][chunk][jl] = acc0;
    red[1][chunk][jl] = acc1;
    __syncthreads();
    if (threadIdx.y < 2 && j < G) {
        const int n = threadIdx.y;
        out[n * (G * NT) + j * NT + t] =
            red[n][0][jl] + red[n][1][jl] + red[n][2][jl] + red[n][3][jl];
    }
}

// ------------- prep: f16x2 canvases + bbox table + zero(out) ---------------
// Block roles by blockIdx.x:
//   [0,81)    : pack image pair into guarded u32 canvases (normal+transposed)
//   [81,115)  : bbox table, one tuple (tg,jb,ib) per thread (8640 tuples)
//   [115,243) : zero out (32670 float4)
__global__ __launch_bounds__(256) void prep_k(
    const float* __restrict__ x, const int* __restrict__ theta,
    unsigned* __restrict__ xIh, unsigned* __restrict__ xTIh,
    int4* __restrict__ bbox, float* __restrict__ out)
{
    const int bid = blockIdx.x;
    const int tx = threadIdx.x, ty = threadIdx.y;
    const int tid = ty * 32 + tx;

    if (bid < 81) {
        __shared__ unsigned tl[32][33];
        const int cx0 = (bid % 9) * 32, cy0 = (bid / 9) * 32;
        #pragma unroll
        for (int dy = 0; dy < 32; dy += 8) {
            const int cy = cy0 + ty + dy, cx = cx0 + tx;
            const int pr = cy - 4, pc = cx - 4;
            unsigned v = 0u;
            if ((unsigned)pr < 256u && (unsigned)pc < 256u) {
                const int p = pr * 256 + pc;
                const unsigned short a = __half_as_ushort(__float2half_rn(x[p]));
                const unsigned short b = __half_as_ushort(__float2half_rn(x[p + 65536]));
                v = (unsigned)a | ((unsigned)b << 16);
            }
            if (cy < CH && cx < CW) xIh[cy * CW + cx] = v;
            tl[ty + dy][tx] = v;
        }
        __syncthreads();
        #pragma unroll
        for (int dy = 0; dy < 32; dy += 8) {
            const int rp = cx0 + ty + dy, cp = cy0 + tx;
            if (rp < CH && cp < CW) xTIh[rp * CW + cp] = tl[tx][ty + dy];
        }
    } else if (bid < 115) {
        const int tuple = (bid - 81) * 256 + tid;
        if (tuple < NTUPLE) {
            const int tg  = tuple / (NJB * NIB), rem = tuple - tg * (NJB * NIB);
            const int jb  = rem / NIB,   ib  = rem - jb * NIB;
            const float thA = (float)theta[tg * 2]     * DEG2RAD;
            const float thB = (float)theta[tg * 2 + 1] * DEG2RAD;
            const float cA = cosf(thA), sA = sinf(thA);
            const float cB = cosf(thB), sB = sinf(thB);
            const float xjm = fmaf((float)(jb * 32),      STEP, -1.0f);
            const float xjM = fmaf((float)(jb * 32 + 31), STEP, -1.0f);
            const float xim = fmaf((float)(ib * 48),      STEP, -1.0f);
            const float xiM = fmaf((float)(ib * 48 + 47), STEP, -1.0f);
            float ixmin = 1e30f, ixmax = -1e30f, iymin = 1e30f, iymax = -1e30f;
            #pragma unroll
            for (int qq = 0; qq < 8; ++qq) {
                const float cc  = (qq & 4) ? cB : cA;
                const float ss  = (qq & 4) ? sB : sA;
                const float xjc = (qq & 1) ? xjM : xjm;
                const float xic = (qq & 2) ? xiM : xim;
                const float bxq = fmaf(cc,  xjc, 1.0f) * 181.0f;
                const float byq = fmaf(-ss, xjc, 1.0f) * 181.0f;
                const float ixq = fmaf(ss * 181.0f, xic, bxq);
                const float iyq = fmaf(cc * 181.0f, xic, byq);
                ixmin = fminf(ixmin, ixq); ixmax = fmaxf(ixmax, ixq);
                iymin = fminf(iymin, iyq); iymax = fmaxf(iymax, iyq);
            }
            const int caseA = (fabsf(cA) + fabsf(cB) >= fabsf(sA) + fabsf(sB));
            const float Umin = caseA ? iymin : ixmin;
            const float Umax = caseA ? iymax : ixmax;
            const float Vmin = caseA ? ixmin : iymin;
            const int r0 = (int)floorf(Umin) - 1;
            const int c0 = (int)floorf(Vmin) - 1;
            int rows = (int)floorf(Umax) - (int)floorf(Umin) + 4;
            rows = min(rows, TROWS);
            const int nchunk = (rows + 3) >> 2;             // 256-cell chunks
            const int r0p = r0 - PADB, c0p = c0 - PADB;
            const int tyLast = (nchunk * 256 - 1) >> 6;     // /TS2
            const int safe = (r0p >= -4) && (r0p + tyLast <= 259)
                          && (c0p >= -4) && (c0p <= 196);
            bbox[tuple] = make_int4(r0p, c0p,
                                    nchunk | (safe << 8) | (caseA << 9),
                                    0);
        }
    } else {
        const int idx = (bid - 115) * 256 + tid;            // out: 130680 f32
        if (idx < 32670) ((float4*)out)[idx] = make_float4(0.f, 0.f, 0.f, 0.f);
    }
}

// ---------------- staging: 16B/lane global_load_lds, linear LDS dest -------
template<bool SAFE>
__device__ __forceinline__ void stage_direct(unsigned* tileB,
    const unsigned* __restrict__ srcC,
    int r0p, int c0p, int nchunk, int wid, int lane)
{
    const int B = (r0p + 4) * CW + (c0p + 4);
    for (int h = wid; h < nchunk; h += 4) {
        const int hs   = __builtin_amdgcn_readfirstlane(h);
        const int cell = (hs << 8) + (lane << 2);   // 4 cells / lane, row-pure
        const int tyc  = cell >> 6;                 // /TS2
        const int txc  = cell & 63;
        int idx;
        if (SAFE) {
            idx = tyc * CW + txc + B;
        } else {
            // clamp into 4-wide zero guard: 16B lane-read stays all-guard
            const int rc = min(max(r0p + tyc, -4), 256) + 4;
            const int cc = min(max(c0p + txc, -4), 256) + 4;
            idx = rc * CW + cc;
        }
        GLOAD16(srcC + idx, (char*)tileB + (hs << 10));
    }
}

// ---------------- gather inner loop (6 i-steps, packed-f16 lerp) -----------
// Cells are __half2 {img0, img1}: both images interpolated per pk-f16 op.
// Two-lerp form == same 4-tap weighted sum (f16-rounded); acc in f16 for
// 6 taps, flushed to f32 by caller-visible a0/a1.
template<bool TAIL>
__device__ __forceinline__ void gather6(const unsigned* __restrict__ tl,
    float Uf0, float Vf0, float dU, float dV, int iexc,
    float& a0, float& a1)
{
    __half2 acc = __float2half2_rn(0.0f);
    #pragma unroll
    for (int k = 0; k < 6; ++k) {
        const float Uf = fmaf((float)k, dU, Uf0);   // independent, no chain
        const float Vf = fmaf((float)k, dV, Vf0);
        const float fU = floorf(Uf), fV = floorf(Vf);
        const float wU1 = Uf - fU;
        const float wV1 = Vf - fV;
        // fU*64+fV exact (small non-neg integers); tile-relative already
        const int rel = (int)fmaf(fU, (float)TS2, fV);
        const __half2 x00 = *(const __half2*)(tl + rel);
        const __half2 x01 = *(const __half2*)(tl + rel + 1);
        const __half2 x10 = *(const __half2*)(tl + rel + TS2);
        const __half2 x11 = *(const __half2*)(tl + rel + TS2 + 1);
        const __half2 wv2 = __float2half2_rn(wV1);
        const __half2 wu2 = __float2half2_rn(wU1);
        const __half2 t0 = __hfma2(wv2, __hsub2(x01, x00), x00);
        const __half2 t1 = __hfma2(wv2, __hsub2(x11, x10), x10);
        __half2 v = __hfma2(wu2, __hsub2(t1, t0), t0);
        if (TAIL && k >= iexc) v = __float2half2_rn(0.0f);   // phantom i >= G
        acc = __hadd2(acc, v);
    }
    a0 += __low2float(acc);
    a1 += __high2float(acc);
}

// ---------------- main tiled gather ----------------------------------------
__global__ __launch_bounds__(256) void radon_tile7(
    const unsigned* __restrict__ xIh, const unsigned* __restrict__ xTIh,
    const int*   __restrict__ theta, const int4* __restrict__ bbox,
    float* __restrict__ out)
{
    __shared__ unsigned tile[NTILE];       // 17,408 B

    const int blk  = blockIdx.x;           // 0..1079
    const int z    = blockIdx.y;           // 0..1, handles ib = 4z..4z+3
    const int tg   = blk / NJB;
    const int jb   = blk - tg * NJB;
    const int tid  = threadIdx.x;
    const int lane = tid & 63;
    const int wid  = tid >> 6;             // 0..3
    const int a    = wid >> 1;             // angle of pair
    const int wj   = wid & 1;              // j half (16)
    const int jl   = lane & 15;            // j lane
    const int kk   = lane >> 4;            // i 12-group (0..3)

    const int t = tg * 2 + a;
    const float th = (float)theta[t] * DEG2RAD;
    const float c = cosf(th), s = sinf(th);
    const float s181 = s * 181.0f, c181 = c * 181.0f;

    const int   j  = jb * 32 + wj * 16 + jl;   // phantom j >= 363 ok
    const float xj = fmaf((float)j, STEP, -1.0f);
    const float bx = fmaf(c,  xj, 1.0f) * 181.0f;
    const float by = fmaf(-s, xj, 1.0f) * 181.0f;

    const float fiofs = (float)(kk * 12);

    // ---- per-pair uniforms (case identical across the subtiles) ----
    const int tb = (tg * NJB + jb) * NIB + z * 4;
    const int caseA = (__builtin_amdgcn_readfirstlane(bbox[tb].z) >> 9) & 1;
    const unsigned* __restrict__ srcC = caseA ? xIh : xTIh;

    const float slopeU = caseA ? c181 : s181;
    const float slopeV = caseA ? s181 : c181;
    const float dU = slopeU * STEP;
    const float dV = slopeV * STEP;
    const float U00 = (caseA ? by : bx) - slopeU;
    const float V00 = (caseA ? bx : by) - slopeV;

    float a0 = 0.f, a1 = 0.f;

    #pragma unroll
    for (int ibi = 0; ibi < 4; ++ibi) {
        const int ib = z * 4 + ibi;
        const int4 bb = bbox[tb + ibi];
        const int r0p    = __builtin_amdgcn_readfirstlane(bb.x);
        const int c0p    = __builtin_amdgcn_readfirstlane(bb.y);
        const int flags  = __builtin_amdgcn_readfirstlane(bb.z);
        const int nchunk = flags & 255;
        const int safe   = (flags >> 8) & 1;

        __syncthreads();                   // previous tile fully consumed

        if (safe) stage_direct<true >(tile, srcC, r0p, c0p, nchunk, wid, lane);
        else      stage_direct<false>(tile, srcC, r0p, c0p, nchunk, wid, lane);
        __syncthreads();                   // drains vmcnt -> tile ready

        // ---- gather: 12 samples/lane as 2x gather6, tile-relative coords --
        const int i0 = ib * 48;
        const float r0f = (float)(r0p + PADB);   // integer subtract: exact
        const float c0f = (float)(c0p + PADB);
        const float fi  = (float)i0 + fiofs;
        const float Uf1 = fmaf(dU, fi, U00) - r0f;
        const float Vf1 = fmaf(dV, fi, V00) - c0f;
        const float Uf2 = fmaf(dU, 6.0f, Uf1);
        const float Vf2 = fmaf(dV, 6.0f, Vf1);
        const int ibase = i0 + kk * 12;

        if (i0 + 47 < G) {                 // block-uniform
            gather6<false>(tile, Uf1, Vf1, dU, dV, 6, a0, a1);
            gather6<false>(tile, Uf2, Vf2, dU, dV, 6, a0, a1);
        } else {
            gather6<true>(tile, Uf1, Vf1, dU, dV, G - ibase,     a0, a1);
            gather6<true>(tile, Uf2, Vf2, dU, dV, G - ibase - 6, a0, a1);
        }
    }

    // ---- reduce i-groups (lanes jl, jl+16, jl+32, jl+48) via shfl ----
    float vx = a0;
    float vy = a1;
    vx += __shfl_xor(vx, 16);
    vy += __shfl_xor(vy, 16);
    vx += __shfl_xor(vx, 32);
    vy += __shfl_xor(vy, 32);

    if (lane < 16 && j < G) {
        atomicAdd(&out[j * NT + t],          vx);   // n = 0
        atomicAdd(&out[G * NT + j * NT + t], vy);   // n = 1
    }
}

extern "C" void kernel_launch(void* const* d_in, const int* in_sizes, int n_in,
                              void* d_out, int out_size, void* d_ws, size_t ws_size,
                              hipStream_t stream) {
    const float* x     = (const float*)d_in[0];
    const int*   theta = (const int*)d_in[1];
    float*       out   = (float*)d_out;

    const size_t XIH_OFF  = 0;
    const size_t XTIH_OFF = (size_t)CH * CW * 4;                 // 278,784
    const size_t BBOX_OFF = 2 * XTIH_OFF;                        // 557,568
    const size_t NEED     = BBOX_OFF + (size_t)NTUPLE * 16;      // ~696 KB

    if (ws_size < NEED) {   // fallback: known-good gather kernel
        hipLaunchKernelGGL(radon_fwd, dim3(NT * NJBF), dim3(64, 4), 0, stream,
                           x, theta, out);
        return;
    }

    unsigned* xIh  = (unsigned*)((char*)d_ws + XIH_OFF);
    unsigned* xTIh = (unsigned*)((char*)d_ws + XTIH_OFF);
    int4*     bbox = (int4*)((char*)d_ws + BBOX_OFF);

    hipLaunchKernelGGL(prep_k, dim3(243), dim3(32, 8), 0, stream,
                       x, theta, xIh, xTIh, bbox, out);
    hipLaunchKernelGGL(radon_tile7, dim3(1080, 2), dim3(256), 0, stream,
                       xIh, xTIh, theta, bbox, out);
}